// Round 7
// baseline (114.453 us; speedup 1.0000x reference)
//
#include <hip/hip_runtime.h>
#include <stdint.h>

#define NI 128
#define NA 285
#define ND 183
#define NT 384
#define RAYS (NA * ND)        // 52155
#define PITCH 133             // dwords per packed row
#define PROWS 132
#define PLDS (PROWS * PITCH)  // 70,224 B -> 2 blocks/CU
#define NPAIR 92              // mirror det-pairs per angle: (j, 182-j)
#define UNITS_PER_J (NA * 2)  // 570: (angle, half) units at fixed j
#define UTOT (NPAIR * UNITS_PER_J)   // 52,440 units per image
#define TPB 832               // 13 waves; 64 blocks/img -> 512 blocks = 2/CU
#define UPB 820               // units per block
#define IDXMAX 17420          // 130*133+130: idx_mirror = IDXMAX - idx

typedef __fp16 half2v __attribute__((ext_vector_type(2)));

constexpr float PI_F  = 3.14159265358979323846f;
constexpr float RHO_F = 28.284271247461902f;   // 20*sqrt(2)
constexpr float DX_F  = 0.3125f;
constexpr float DT_F  = 2.0f * RHO_F / NT;

// Mirror-paired + chord-split Radon, 4-way software-pipelined inner loop.
// Each lane: mirror-pair (a,j)/(a,182-j), half chord (h=0 walks down from
// chord middle, h=1 walks up). Over-run samples exit the support square ->
// clamp lands them in the 2-cell zero ring -> contribute exactly 0. The 4
// in-flight samples are fully independent chains so LDS latency pipelines.
__device__ __forceinline__ void sample_step(const unsigned int* P,
                                            float q0, float q1,
                                            float& accL, float& accR) {
    q0 = fminf(fmaxf(q0, 0.5f), 130.49f);   // v_med3
    q1 = fminf(fmaxf(q1, 0.5f), 130.49f);
    float f0 = floorf(q0);
    float f1 = floorf(q1);
    float a0 = q0 - f0;
    float a1 = q1 - f1;
    int idx = (int)fmaf(f0, (float)PITCH, f1);   // exact (< 2^24)
    unsigned int u0 = P[idx];
    unsigned int u1 = P[idx + 1];
    unsigned int m0 = P[IDXMAX - idx];           // mirror ray, flipped
    unsigned int m1 = P[IDXMAX - idx + 1];
    unsigned int wb = __builtin_bit_cast(unsigned int,
                          __builtin_amdgcn_cvt_pkrtz(1.0f - a0, a0));
    unsigned int wbm = __builtin_amdgcn_alignbit(wb, wb, 16);  // swap halves
    half2v w  = __builtin_bit_cast(half2v, wb);
    half2v wm = __builtin_bit_cast(half2v, wbm);
    float lL = __builtin_amdgcn_fdot2(__builtin_bit_cast(half2v, u0), w, 0.0f, false);
    float rL = __builtin_amdgcn_fdot2(__builtin_bit_cast(half2v, u1), w, 0.0f, false);
    float lR = __builtin_amdgcn_fdot2(__builtin_bit_cast(half2v, m0), wm, 0.0f, false);
    float rR = __builtin_amdgcn_fdot2(__builtin_bit_cast(half2v, m1), wm, 0.0f, false);
    accL += fmaf(a1, rL - lL, lL);
    accR += fmaf(a1, lR - rR, rR);   // == lR*a1 + rR*(1-a1)
}

__global__ __launch_bounds__(TPB) void radon_fwd(const float* __restrict__ x,
                                                 float* __restrict__ out) {
    __shared__ __align__(16) unsigned int P[PLDS];
    const int tid   = threadIdx.x;
    const int img   = blockIdx.x >> 6;
    const int chunk = blockIdx.x & 63;

    uint4* P4 = (uint4*)P;
    for (int i = tid; i < PLDS / 4; i += TPB) P4[i] = make_uint4(0, 0, 0, 0);
    __syncthreads();

    // Vertical-pair pack: P[pr*133+pc] = half2(pad[pr][pc], pad[pr+1][pc]),
    // pad = image with 2-cell zero ring (pad row/col = image index + 2).
    const float4* src = (const float4*)(x + img * NI * NI);
    for (int i = tid; i < 129 * 32; i += TPB) {
        int pr  = 1 + (i >> 5);
        int g   = i & 31;
        int rlo = pr - 2;
        int rhi = pr - 1;
        float4 vlo = (rlo >= 0)   ? src[rlo * 32 + g] : make_float4(0, 0, 0, 0);
        float4 vhi = (rhi <= 127) ? src[rhi * 32 + g] : make_float4(0, 0, 0, 0);
        int base = pr * PITCH + 2 + g * 4;
        P[base + 0] = __builtin_bit_cast(unsigned int, __builtin_amdgcn_cvt_pkrtz(vlo.x, vhi.x));
        P[base + 1] = __builtin_bit_cast(unsigned int, __builtin_amdgcn_cvt_pkrtz(vlo.y, vhi.y));
        P[base + 2] = __builtin_bit_cast(unsigned int, __builtin_amdgcn_cvt_pkrtz(vlo.z, vhi.z));
        P[base + 3] = __builtin_bit_cast(unsigned int, __builtin_amdgcn_cvt_pkrtz(vlo.w, vhi.w));
    }
    __syncthreads();

    const int  u     = chunk * UPB + tid;
    const bool valid = (tid < UPB) && (u < UTOT);
    const int j = u / UNITS_PER_J;            // magic-multiply
    const int r = u - j * UNITS_PER_J;
    const int a = r >> 1;                     // angle
    const int h = r & 1;                      // chord half (0=down, 1=up)

    const float ang = ((float)a + 0.5f) * (PI_F / (float)NA);
    float sn, cs;
    sincosf(ang, &sn, &cs);
    const float s   = -RHO_F + ((float)j + 0.5f) * (2.0f * RHO_F / (float)ND);
    const float t0v = -RHO_F + 0.5f * DT_F;
    const float inv_dx = 1.0f / DX_F;

    const float e0 = -s * sn;
    const float e1 =  s * cs;
    const float c0  = (e0 + t0v * cs + 20.0f) * inv_dx + 1.5f;
    const float c1  = (e1 + t0v * sn + 20.0f) * inv_dx + 1.5f;
    const float st0 = DT_F * cs * inv_dx;
    const float st1 = DT_F * sn * inv_dx;

    // Clip to bilinear support |p| <= 20 + DX/2 (+ fp margin).
    const float LIM = 20.157f;
    const float inv_cs = 1.0f / cs;
    const float inv_sn = 1.0f / sn;
    float ta = (-LIM - e0) * inv_cs, tb = (LIM - e0) * inv_cs;
    float tc = (-LIM - e1) * inv_sn, td = (LIM - e1) * inv_sn;
    float tlo = fmaxf(fminf(ta, tb), fminf(tc, td));
    float thi = fminf(fmaxf(ta, tb), fmaxf(tc, td));

    const float inv_dt = 1.0f / DT_F;
    float fk0 = fminf(fmaxf(ceilf((tlo - t0v) * inv_dt), 0.0f), 384.0f);
    float fk1 = fminf(fmaxf(floorf((thi - t0v) * inv_dt), -1.0f), 383.0f);
    const int kmin = (int)fk0;
    const int kmax = (int)fk1;
    const int kmid = (kmin + kmax + 1) >> 1;

    int mylen = h ? (kmax - kmid + 1) : (kmid - kmin);
    if (mylen < 0 || !valid) mylen = 0;

    // Wave envelope (lanes = adjacent angles at fixed j -> tight).
    int Lw = mylen;
    #pragma unroll
    for (int off = 32; off >= 1; off >>= 1)
        Lw = max(Lw, __shfl_xor(Lw, off, 64));

    const float sgn  = h ? 1.0f : -1.0f;
    const float st0h = st0 * sgn;
    const float st1h = st1 * sgn;
    const float ks   = (float)(h ? kmid : kmid - 1);

    // 4 independent in-flight sample coordinates.
    float i0a = fmaf(ks, st0, c0);
    float i1a = fmaf(ks, st1, c1);
    float i0b = i0a + st0h, i1b = i1a + st1h;
    float i0c = i0b + st0h, i1c = i1b + st1h;
    float i0d = i0c + st0h, i1d = i1c + st1h;
    const float j0 = 4.0f * st0h;
    const float j1 = 4.0f * st1h;
    float accL0 = 0.0f, accR0 = 0.0f, accL1 = 0.0f, accR1 = 0.0f;

    #pragma unroll 1
    for (int m = 0; m < Lw; m += 4) {
        sample_step(P, i0a, i1a, accL0, accR0);
        sample_step(P, i0b, i1b, accL1, accR1);
        sample_step(P, i0c, i1c, accL0, accR0);
        sample_step(P, i0d, i1d, accL1, accR1);
        i0a += j0; i1a += j1;
        i0b += j0; i1b += j1;
        i0c += j0; i1c += j1;
        i0d += j0; i1d += j1;
    }
    float accL = accL0 + accL1;
    float accR = accR0 + accR1;

    // Combine the two chord halves (adjacent lanes).
    accL += __shfl_xor(accL, 1, 64);
    accR += __shfl_xor(accR, 1, 64);

    if (valid) {
        const float sc = DT_F / 12.0f;
        const int base = img * RAYS + a * ND;
        int det = h ? (182 - j) : j;
        float v = h ? accR : accL;
        out[base + det] = v * sc;
    }
}

extern "C" void kernel_launch(void* const* d_in, const int* in_sizes, int n_in,
                              void* d_out, int out_size, void* d_ws, size_t ws_size,
                              hipStream_t stream) {
    const float* x = (const float*)d_in[0];
    float* out = (float*)d_out;
    const int B = in_sizes[0] / (NI * NI);   // 8
    dim3 grid(B * 64);
    radon_fwd<<<grid, TPB, 0, stream>>>(x, out);
}

// Round 8
// 99.105 us; speedup vs baseline: 1.1549x; 1.1549x over previous
//
#include <hip/hip_runtime.h>
#include <stdint.h>

#define NI 128
#define NA 285
#define ND 183
#define NT 384
#define RAYS (NA * ND)        // 52155
#define PITCH 133             // dwords per packed row
#define PROWS 132
#define PLDS (PROWS * PITCH)  // 70,224 B
#define TPB 832               // 13 waves; grid 64 blocks/img
#define NTASK 828             // 92 j-values x 9 angle-chunks (32 angles each)
#define IDXMAX 17420          // 130*133+130: idx_mirror = IDXMAX - idx

typedef __fp16 half2v __attribute__((ext_vector_type(2)));

constexpr float PI_F  = 3.14159265358979323846f;
constexpr float RHO_F = 28.284271247461902f;   // 20*sqrt(2)
constexpr float DX_F  = 0.3125f;
constexpr float DT_F  = 2.0f * RHO_F / NT;

// Per-sample phase 1: clamp/floor/index + the 4 LDS dwords (primary pair +
// mirror pair). Kept separate from phase 2 so the 4-way group issues all 16
// loads before any fdot2 consumes them (LDS latency pipelining).
struct Smp { float a0, a1; unsigned int u0, u1, m0, m1; };

__device__ __forceinline__ Smp phase1(const unsigned int* P, float q0, float q1) {
    q0 = fminf(fmaxf(q0, 0.5f), 130.49f);   // v_med3; OOB -> zero ring
    q1 = fminf(fmaxf(q1, 0.5f), 130.49f);
    float f0 = floorf(q0);
    float f1 = floorf(q1);
    Smp s;
    s.a0 = q0 - f0;
    s.a1 = q1 - f1;
    int idx = (int)fmaf(f0, (float)PITCH, f1);   // exact (< 2^24)
    s.u0 = P[idx];
    s.u1 = P[idx + 1];
    s.m0 = P[IDXMAX - idx];
    s.m1 = P[IDXMAX - idx + 1];
    return s;
}

__device__ __forceinline__ void phase2(const Smp& s, float& accL, float& accR) {
    unsigned int wb = __builtin_bit_cast(unsigned int,
                          __builtin_amdgcn_cvt_pkrtz(1.0f - s.a0, s.a0));
    unsigned int wbm = __builtin_amdgcn_alignbit(wb, wb, 16);  // swap halves
    half2v w  = __builtin_bit_cast(half2v, wb);
    half2v wm = __builtin_bit_cast(half2v, wbm);
    float lL = __builtin_amdgcn_fdot2(__builtin_bit_cast(half2v, s.u0), w, 0.0f, false);
    float rL = __builtin_amdgcn_fdot2(__builtin_bit_cast(half2v, s.u1), w, 0.0f, false);
    float lR = __builtin_amdgcn_fdot2(__builtin_bit_cast(half2v, s.m0), wm, 0.0f, false);
    float rR = __builtin_amdgcn_fdot2(__builtin_bit_cast(half2v, s.m1), wm, 0.0f, false);
    accL += fmaf(s.a1, rL - lL, lL);
    accR += fmaf(s.a1, lR - rR, rR);   // == lR*a1 + rR*(1-a1)
}

// Mirror-paired + chord-split Radon with j-interleaved static schedule:
// wave w of block chunk owns task t = w*64 + chunk; j = t/9 spreads over the
// full detector range within every block -> per-block work equalized.
// Wave = 32 adjacent angles x 2 chord-halves at fixed j (tight envelope).
__global__ __launch_bounds__(TPB) void radon_fwd(const float* __restrict__ x,
                                                 float* __restrict__ out) {
    __shared__ __align__(16) unsigned int P[PLDS];
    const int tid   = threadIdx.x;
    const int img   = blockIdx.x >> 6;
    const int chunk = blockIdx.x & 63;

    uint4* P4 = (uint4*)P;
    for (int i = tid; i < PLDS / 4; i += TPB) P4[i] = make_uint4(0, 0, 0, 0);
    __syncthreads();

    // Vertical-pair pack: P[pr*133+pc] = half2(pad[pr][pc], pad[pr+1][pc]),
    // pad = image with 2-cell zero ring (pad row/col = image index + 2).
    const float4* src = (const float4*)(x + img * NI * NI);
    for (int i = tid; i < 129 * 32; i += TPB) {
        int pr  = 1 + (i >> 5);
        int g   = i & 31;
        int rlo = pr - 2;
        int rhi = pr - 1;
        float4 vlo = (rlo >= 0)   ? src[rlo * 32 + g] : make_float4(0, 0, 0, 0);
        float4 vhi = (rhi <= 127) ? src[rhi * 32 + g] : make_float4(0, 0, 0, 0);
        int base = pr * PITCH + 2 + g * 4;
        P[base + 0] = __builtin_bit_cast(unsigned int, __builtin_amdgcn_cvt_pkrtz(vlo.x, vhi.x));
        P[base + 1] = __builtin_bit_cast(unsigned int, __builtin_amdgcn_cvt_pkrtz(vlo.y, vhi.y));
        P[base + 2] = __builtin_bit_cast(unsigned int, __builtin_amdgcn_cvt_pkrtz(vlo.z, vhi.z));
        P[base + 3] = __builtin_bit_cast(unsigned int, __builtin_amdgcn_cvt_pkrtz(vlo.w, vhi.w));
    }
    __syncthreads();

    const int w_id = tid >> 6;
    const int lane = tid & 63;
    const int t    = w_id * 64 + chunk;       // j-interleaved task id
    const int j    = t / 9;                   // detector pair index (0..91)
    const int c    = t - j * 9;               // angle chunk (0..8)
    const int a    = c * 32 + (lane >> 1);    // angle
    const int h    = lane & 1;                // chord half (0=down, 1=up)
    const bool valid = (t < NTASK) && (a < NA);

    const float ang = ((float)a + 0.5f) * (PI_F / (float)NA);
    float sn, cs;
    sincosf(ang, &sn, &cs);
    const float s   = -RHO_F + ((float)j + 0.5f) * (2.0f * RHO_F / (float)ND);
    const float t0v = -RHO_F + 0.5f * DT_F;
    const float inv_dx = 1.0f / DX_F;

    const float e0 = -s * sn;
    const float e1 =  s * cs;
    const float c0  = (e0 + t0v * cs + 20.0f) * inv_dx + 1.5f;
    const float c1  = (e1 + t0v * sn + 20.0f) * inv_dx + 1.5f;
    const float st0 = DT_F * cs * inv_dx;
    const float st1 = DT_F * sn * inv_dx;

    // Clip to bilinear support |p| <= 20 + DX/2 (+ fp margin).
    const float LIM = 20.157f;
    const float inv_cs = 1.0f / cs;
    const float inv_sn = 1.0f / sn;
    float ta = (-LIM - e0) * inv_cs, tb = (LIM - e0) * inv_cs;
    float tc = (-LIM - e1) * inv_sn, td = (LIM - e1) * inv_sn;
    float tlo = fmaxf(fminf(ta, tb), fminf(tc, td));
    float thi = fminf(fmaxf(ta, tb), fmaxf(tc, td));

    const float inv_dt = 1.0f / DT_F;
    float fk0 = fminf(fmaxf(ceilf((tlo - t0v) * inv_dt), 0.0f), 384.0f);
    float fk1 = fminf(fmaxf(floorf((thi - t0v) * inv_dt), -1.0f), 383.0f);
    const int kmin = (int)fk0;
    const int kmax = (int)fk1;
    const int kmid = (kmin + kmax + 1) >> 1;

    int mylen = h ? (kmax - kmid + 1) : (kmid - kmin);
    if (mylen < 0 || !valid) mylen = 0;

    // Wave envelope (lanes = adjacent angles at fixed j -> tight).
    int Lw = mylen;
    #pragma unroll
    for (int off = 32; off >= 1; off >>= 1)
        Lw = max(Lw, __shfl_xor(Lw, off, 64));

    const float sgn  = h ? 1.0f : -1.0f;
    const float st0h = st0 * sgn;
    const float st1h = st1 * sgn;
    const float ks   = (float)(h ? kmid : kmid - 1);

    // 4 independent in-flight sample coordinates (walk outward from chord
    // middle; over-run samples clamp into the zero ring -> contribute 0).
    float i0a = fmaf(ks, st0, c0);
    float i1a = fmaf(ks, st1, c1);
    float i0b = i0a + st0h, i1b = i1a + st1h;
    float i0c = i0b + st0h, i1c = i1b + st1h;
    float i0d = i0c + st0h, i1d = i1c + st1h;
    const float j0 = 4.0f * st0h;
    const float j1 = 4.0f * st1h;
    float accL0 = 0.0f, accR0 = 0.0f, accL1 = 0.0f, accR1 = 0.0f;

    #pragma unroll 1
    for (int m = 0; m < Lw; m += 4) {
        Smp sa = phase1(P, i0a, i1a);
        Smp sb = phase1(P, i0b, i1b);
        Smp sc = phase1(P, i0c, i1c);
        Smp sd = phase1(P, i0d, i1d);
        i0a += j0; i1a += j1;
        i0b += j0; i1b += j1;
        i0c += j0; i1c += j1;
        i0d += j0; i1d += j1;
        phase2(sa, accL0, accR0);
        phase2(sb, accL1, accR1);
        phase2(sc, accL0, accR0);
        phase2(sd, accL1, accR1);
    }
    float accL = accL0 + accL1;
    float accR = accR0 + accR1;

    // Combine the two chord halves (adjacent lanes share a, differ in h).
    accL += __shfl_xor(accL, 1, 64);
    accR += __shfl_xor(accR, 1, 64);

    if (valid) {
        const float sc = DT_F / 12.0f;
        const int base = img * RAYS + a * ND;
        int det = h ? (182 - j) : j;
        float v = h ? accR : accL;
        out[base + det] = v * sc;
    }
}

extern "C" void kernel_launch(void* const* d_in, const int* in_sizes, int n_in,
                              void* d_out, int out_size, void* d_ws, size_t ws_size,
                              hipStream_t stream) {
    const float* x = (const float*)d_in[0];
    float* out = (float*)d_out;
    const int B = in_sizes[0] / (NI * NI);   // 8
    dim3 grid(B * 64);
    radon_fwd<<<grid, TPB, 0, stream>>>(x, out);
}